// Round 11
// baseline (1804.801 us; speedup 1.0000x reference)
//
#include <hip/hip_runtime.h>

#define BB 64
#define TT 4995
#define VV 4096
#define EE 100
#define UU 64
#define U3 192
#define BPB 4             // batch rows per block (spread across D lane-groups)
#define NBLK (BB / BPB)   // 16 blocks

using bf16x8 = __attribute__((ext_vector_type(8))) short;
using f32x4  = __attribute__((ext_vector_type(4))) float;
// 4B-aligned float4 for the packed 12B gate-triple load (may straddle 16B)
typedef float f32x4u __attribute__((ext_vector_type(4), aligned(4)));

#define MFMA16 __builtin_amdgcn_mfma_f32_16x16x32_bf16

// Static device workspace, gate-interleaved: embW[v][unit u][g] (g=0:z,1:r,2:h)
// = (emb @ W1 + b1[0])[v][g*64+u]. 3.07 MB, L2-resident. +4 floats pad so the
// last lane's 16B vector load (12B used) stays in bounds.
__device__ float g_embW[VV * U3 + 4];

__device__ __forceinline__ float fast_sigmoid(float x) {
    return __builtin_amdgcn_rcpf(1.0f + __expf(-x));
}
__device__ __forceinline__ float fast_tanh(float x) {
    return __builtin_amdgcn_rcpf(1.0f + __expf(-2.0f * x)) * 2.0f - 1.0f;
}
// f32 -> bf16 round-to-nearest-even
__device__ __forceinline__ unsigned short f2bf(float f) {
    unsigned u = __float_as_uint(f);
    return (unsigned short)((u + 0x7FFFu + ((u >> 16) & 1u)) >> 16);
}
__device__ __forceinline__ float bf2f(unsigned short h) {
    return __uint_as_float(((unsigned)h) << 16);
}

// Kernel A: embW[v][u][g] = sum_j emb[v][j] * W1[j][g*64+u] + b1[0][g*64+u]
__global__ void gru_embw_kernel(const float* __restrict__ emb,
                                const float* __restrict__ W1,
                                const float* __restrict__ b1) {
    __shared__ float row[EE];
    const int v = blockIdx.x;
    const int k = threadIdx.x;  // 0..191 = original column (g*64+u)
    if (k < EE) row[k] = emb[v * EE + k];
    __syncthreads();
    float acc = b1[k];
    #pragma unroll 4
    for (int j = 0; j < EE; ++j)
        acc = fmaf(row[j], W1[j * U3 + k], acc);
    const int g = k >> 6;       // gate
    const int u = k & 63;       // unit
    g_embW[v * U3 + u * 3 + g] = acc;   // gate-interleaved store
}

// Kernel B: MFMA-based fused 2-layer GRU scan, 16 blocks x 4 batch rows.
// Structure = R4 VERBATIM (verified best, 1609 us: __syncthreads barrier,
// depth-2 xp/token pipeline, chained MFMAs). R10 delta (ONE mechanism):
// the 3 per-step embW gate loads (cols 64 apart, 3 addr chains) become ONE
// 12-byte vector load from the gate-interleaved table above. Cuts ~2 global
// loads + ~10 VALU addressing ops per L1 lane per step of pure issue.
__global__ __launch_bounds__(512, 1)
void gru_scan_kernel(const int* __restrict__ tokens,
                     const float* __restrict__ U1,
                     const float* __restrict__ b1,
                     const float* __restrict__ W2,
                     const float* __restrict__ U2,
                     const float* __restrict__ b2,
                     const float* __restrict__ Wout,
                     const float* __restrict__ bout,
                     float* __restrict__ out) {
    const int blk  = blockIdx.x;
    const int tid  = threadIdx.x;
    const int wave = tid >> 6;
    const int lane = tid & 63;
    const int lg   = lane >> 4;   // 0..3: k-chunk group (A/B), row group (D)
    const int lc   = lane & 15;   // 0..15: A-row / D-col
    const bool isL2 = (wave >= 4);
    const int ut   = wave & 3;    // unit tile (16 units) this wave owns

    // h state: [buf(2)][which(2: h1,h2)][row 16][unit 64] bf16, XOR-swizzled:
    // byte = ((buf*2+which)*16 + row)*128 + ((unit*2) ^ ((row&7)<<4))
    // Rows != 0,4,8,12 are never written -> stay zero (harmless in MFMA).
    __shared__ __align__(16) char hls[8192];
    for (int i = tid; i < 2048; i += 512) ((int*)hls)[i] = 0;

    // ---- weight B-fragments (once). k-map: k = 8*lg + 32*kk + e.
    // A uses the same k-map, so any HW k-permutation cancels (A/B mirrored).
    bf16x8 fb[12];
    const int cz = ut * 16 + lc;          // z gate column
    const int cr = 64 + ut * 16 + lc;     // r gate column
    const int ch = 128 + ut * 16 + lc;    // hh gate column
    {
        const float* M0 = isL2 ? W2 : U1;
        #pragma unroll
        for (int g = 0; g < 3; ++g) {
            const int col = g * 64 + ut * 16 + lc;
            #pragma unroll
            for (int kk = 0; kk < 2; ++kk) {
                bf16x8 v;
                #pragma unroll
                for (int e = 0; e < 8; ++e)
                    v[e] = (short)f2bf(M0[(8 * lg + 32 * kk + e) * U3 + col]);
                fb[g * 2 + kk] = v;
            }
        }
        if (isL2) {
            #pragma unroll
            for (int g = 0; g < 3; ++g) {
                const int col = g * 64 + ut * 16 + lc;
                #pragma unroll
                for (int kk = 0; kk < 2; ++kk) {
                    bf16x8 v;
                    #pragma unroll
                    for (int e = 0; e < 8; ++e)
                        v[e] = (short)f2bf(U2[(8 * lg + 32 * kk + e) * U3 + col]);
                    fb[6 + g * 2 + kk] = v;
                }
            }
        } else {
            #pragma unroll
            for (int q = 6; q < 12; ++q) fb[q] = fb[q - 6];  // keep defined
        }
    }

    // biases (per-column, constant over rows)
    float bias_z, bias_r, bias_h, bias_h2 = 0.0f;
    if (!isL2) {
        bias_z = b1[U3 + cz]; bias_r = b1[U3 + cr]; bias_h = b1[U3 + ch];
    } else {
        bias_z  = b2[cz] + b2[U3 + cz];
        bias_r  = b2[cr] + b2[U3 + cr];
        bias_h  = b2[ch];         // xh accumulator init (input-side bias)
        bias_h2 = b2[U3 + ch];    // hph accumulator init (recurrent bias)
    }

    // ---- xp/token prefetch pipeline (L1 waves), depth 2 as in R4.
    // xp4[q].x/.y/.z = (z,r,h) gate triple, ONE 12B load per step.
    f32x4u xp4[2];
    int   tok[2];
    const int rowbase = (blk * BPB + lg) * TT;   // this lane's token row
    const char* embB = (const char*)g_embW;
    const int coff = (ut * 16 + lc) * 12;        // byte offset of unit triple
    if (!isL2) {
        const int t0 = tokens[rowbase];
        tok[0] = tokens[rowbase + 1];
        tok[1] = tokens[rowbase + 2];
        xp4[0] = *(const f32x4u*)(embB + t0 * 768 + coff);
        xp4[1] = xp4[0];                         // defined; overwritten at s=0
    }

    float h1o = 0.0f;   // h1(s-1) master copy (L1 waves)
    float h2o = 0.0f;   // h2(s-2) master copy (L2 waves)

    __syncthreads();

    const int swzA = (lc & 7) << 4;              // A-read row swizzle (row = lc)
    const int myrow = 4 * lg;                    // this lane's MFMA/LDS row
    const int wswz  = ((myrow & 7) << 4);        // write swizzle for that row
    const int wbyte = myrow * 128 + (((ut * 16 + lc) * 2) ^ wswz);

    #pragma unroll 1
    for (int sb = 0; sb < TT + 1; sb += 2) {      // TT+1 = 4996 steps total
        #pragma unroll
        for (int half = 0; half < 2; ++half) {
            const int s = sb + half;              // step
            char* rdb = hls + half * 4096;        // read buffer
            char* wrb = hls + (half ^ 1) * 4096;  // write buffer

            // A-fragments: rows=batch (lc), k=units. One ds_read_b128 each.
            bf16x8 a1_0 = *(const bf16x8*)(rdb + lc * 128 + ((16 * lg) ^ swzA));
            bf16x8 a1_1 = *(const bf16x8*)(rdb + lc * 128 + ((16 * lg + 64) ^ swzA));
            bf16x8 a2_0 = *(const bf16x8*)(rdb + 2048 + lc * 128 + ((16 * lg) ^ swzA));
            bf16x8 a2_1 = *(const bf16x8*)(rdb + 2048 + lc * 128 + ((16 * lg + 64) ^ swzA));

            if (!isL2) {
                // prefetch xp for step s+1 (uses tok[half] = tokens[s+1]),
                // and tokens for s+2 into tok[half^1] — ONE 12B load now
                const int tn = tok[half];
                xp4[half ^ 1] = *(const f32x4u*)(embB + tn * 768 + coff);
                const int s2 = (s + 2 < TT) ? (s + 2) : (TT - 1);
                tok[half ^ 1] = tokens[rowbase + s2];

                if (s < TT) {   // layer 1 computes h1(s)
                    f32x4 az = {bias_z, bias_z, bias_z, bias_z};
                    f32x4 ar = {bias_r, bias_r, bias_r, bias_r};
                    f32x4 ah = {bias_h, bias_h, bias_h, bias_h};
                    az = MFMA16(a1_0, fb[0], az, 0, 0, 0);
                    az = MFMA16(a1_1, fb[1], az, 0, 0, 0);
                    ar = MFMA16(a1_0, fb[2], ar, 0, 0, 0);
                    ar = MFMA16(a1_1, fb[3], ar, 0, 0, 0);
                    ah = MFMA16(a1_0, fb[4], ah, 0, 0, 0);
                    ah = MFMA16(a1_1, fb[5], ah, 0, 0, 0);
                    const float z  = fast_sigmoid(xp4[half].x + az[0]);
                    const float rg = fast_sigmoid(xp4[half].y + ar[0]);
                    const float hh = fast_tanh(xp4[half].z + rg * ah[0]);
                    h1o = z * h1o + (1.0f - z) * hh;
                    *(unsigned short*)(wrb + wbyte) = f2bf(h1o);
                }
            } else {
                if (s > 0) {    // layer 2 computes h2(s-1)
                    f32x4 az = {bias_z,  bias_z,  bias_z,  bias_z };
                    f32x4 ar = {bias_r,  bias_r,  bias_r,  bias_r };
                    f32x4 ax = {bias_h,  bias_h,  bias_h,  bias_h };
                    f32x4 ap = {bias_h2, bias_h2, bias_h2, bias_h2};
                    az = MFMA16(a1_0, fb[0],  az, 0, 0, 0);   // h1@W2 (z)
                    az = MFMA16(a1_1, fb[1],  az, 0, 0, 0);
                    az = MFMA16(a2_0, fb[6],  az, 0, 0, 0);   // + h2@U2 (z)
                    az = MFMA16(a2_1, fb[7],  az, 0, 0, 0);
                    ar = MFMA16(a1_0, fb[2],  ar, 0, 0, 0);
                    ar = MFMA16(a1_1, fb[3],  ar, 0, 0, 0);
                    ar = MFMA16(a2_0, fb[8],  ar, 0, 0, 0);
                    ar = MFMA16(a2_1, fb[9],  ar, 0, 0, 0);
                    ax = MFMA16(a1_0, fb[4],  ax, 0, 0, 0);   // xh (input side)
                    ax = MFMA16(a1_1, fb[5],  ax, 0, 0, 0);
                    ap = MFMA16(a2_0, fb[10], ap, 0, 0, 0);   // hph (recurrent)
                    ap = MFMA16(a2_1, fb[11], ap, 0, 0, 0);
                    const float z  = fast_sigmoid(az[0]);
                    const float rg = fast_sigmoid(ar[0]);
                    const float hh = fast_tanh(ax[0] + rg * ap[0]);
                    h2o = z * h2o + (1.0f - z) * hh;
                    *(unsigned short*)(wrb + 2048 + wbyte) = f2bf(h2o);
                }
            }
            __syncthreads();
        }
    }

    // ---- output head: h2(TT-1) sits in buf0/which=1 (step TT wrote buf0).
    // Lane j (0..3) of wave 0 handles batch row j at LDS row 4*j.
    if (wave == 0 && lane < BPB) {
        const int row = 4 * lane;
        float acc = bout[0];
        #pragma unroll 8
        for (int u = 0; u < UU; ++u) {
            const unsigned short hv = *(const unsigned short*)(hls + 2048 +
                row * 128 + ((u * 2) ^ ((row & 7) << 4)));
            acc = fmaf(bf2f(hv), Wout[u], acc);
        }
        out[blk * BPB + lane] = fast_sigmoid(acc);
    }
}

extern "C" void kernel_launch(void* const* d_in, const int* in_sizes, int n_in,
                              void* d_out, int out_size, void* d_ws, size_t ws_size,
                              hipStream_t stream) {
    const int*   tokens = (const int*)  d_in[0];
    const float* emb    = (const float*)d_in[1];
    const float* W1     = (const float*)d_in[2];
    const float* U1w    = (const float*)d_in[3];
    const float* b1     = (const float*)d_in[4];
    const float* W2     = (const float*)d_in[5];
    const float* U2w    = (const float*)d_in[6];
    const float* b2     = (const float*)d_in[7];
    const float* Wout   = (const float*)d_in[8];
    const float* bout   = (const float*)d_in[9];
    float* out = (float*)d_out;

    gru_embw_kernel<<<VV, 192, 0, stream>>>(emb, W1, b1);
    gru_scan_kernel<<<NBLK, 512, 0, stream>>>(tokens, U1w, b1, W2, U2w,
                                              b2, Wout, bout, out);
}

// Round 12
// 1615.018 us; speedup vs baseline: 1.1175x; 1.1175x over previous
//
#include <hip/hip_runtime.h>

#define BB 64
#define TT 4995
#define VV 4096
#define EE 100
#define UU 64
#define U3 192
#define BPB 4             // batch rows per block (spread across D lane-groups)
#define NBLK (BB / BPB)   // 16 blocks

using bf16x8 = __attribute__((ext_vector_type(8))) short;
using f32x4  = __attribute__((ext_vector_type(4))) float;

#define MFMA16 __builtin_amdgcn_mfma_f32_16x16x32_bf16

// Static device workspace: embW[v][k] = (emb @ W1 + b1[0])[v][k], 3.07 MB (L2-resident).
__device__ float g_embW[VV * U3];

__device__ __forceinline__ float fast_sigmoid(float x) {
    return __builtin_amdgcn_rcpf(1.0f + __expf(-x));
}
__device__ __forceinline__ float fast_tanh(float x) {
    return __builtin_amdgcn_rcpf(1.0f + __expf(-2.0f * x)) * 2.0f - 1.0f;
}
// f32 -> bf16 round-to-nearest-even
__device__ __forceinline__ unsigned short f2bf(float f) {
    unsigned u = __float_as_uint(f);
    return (unsigned short)((u + 0x7FFFu + ((u >> 16) & 1u)) >> 16);
}
__device__ __forceinline__ float bf2f(unsigned short h) {
    return __uint_as_float(((unsigned)h) << 16);
}

// Kernel A: embW[v][k] = sum_j emb[v][j] * W1[j][k] + b1[0][k]  (fp32 table)
__global__ void gru_embw_kernel(const float* __restrict__ emb,
                                const float* __restrict__ W1,
                                const float* __restrict__ b1) {
    __shared__ float row[EE];
    const int v = blockIdx.x;
    const int k = threadIdx.x;  // 0..191
    if (k < EE) row[k] = emb[v * EE + k];
    __syncthreads();
    float acc = b1[k];
    #pragma unroll 4
    for (int j = 0; j < EE; ++j)
        acc = fmaf(row[j], W1[j * U3 + k], acc);
    g_embW[v * U3 + k] = acc;
}

// Kernel B: MFMA-based fused 2-layer GRU scan, 16 blocks x 4 batch rows.
// == R4 VERBATIM (verified best of the session, 1609 us). ==
// Batch row rb (0..3) lives at MFMA/LDS row 4*rb, so in the D layout
// (col=lane&15, row=(lane>>4)*4+reg) every lane owns EXACTLY ONE valid
// (row,unit) at reg 0 -> one gate computation per lane per step.
// Waves 0-3 = layer1 unit-tile ut, waves 4-7 = layer2 unit-tile ut.
// Weights persist in registers as B-fragments; h-state crosses steps via
// XOR-swizzled bf16 LDS (double-buffered, ONE barrier/step). Layer2 lags
// layer1 by one step.
__global__ __launch_bounds__(512, 1)
void gru_scan_kernel(const int* __restrict__ tokens,
                     const float* __restrict__ U1,
                     const float* __restrict__ b1,
                     const float* __restrict__ W2,
                     const float* __restrict__ U2,
                     const float* __restrict__ b2,
                     const float* __restrict__ Wout,
                     const float* __restrict__ bout,
                     float* __restrict__ out) {
    const int blk  = blockIdx.x;
    const int tid  = threadIdx.x;
    const int wave = tid >> 6;
    const int lane = tid & 63;
    const int lg   = lane >> 4;   // 0..3: k-chunk group (A/B), row group (D)
    const int lc   = lane & 15;   // 0..15: A-row / D-col
    const bool isL2 = (wave >= 4);
    const int ut   = wave & 3;    // unit tile (16 units) this wave owns

    // h state: [buf(2)][which(2: h1,h2)][row 16][unit 64] bf16, XOR-swizzled:
    // byte = ((buf*2+which)*16 + row)*128 + ((unit*2) ^ ((row&7)<<4))
    // Rows != 0,4,8,12 are never written -> stay zero (harmless in MFMA).
    __shared__ __align__(16) char hls[8192];
    for (int i = tid; i < 2048; i += 512) ((int*)hls)[i] = 0;

    // ---- weight B-fragments (once). k-map: k = 8*lg + 32*kk + e.
    // A uses the same k-map, so any HW k-permutation cancels (A/B mirrored).
    bf16x8 fb[12];
    const int cz = ut * 16 + lc;          // z gate column
    const int cr = 64 + ut * 16 + lc;     // r gate column
    const int ch = 128 + ut * 16 + lc;    // hh gate column
    {
        const float* M0 = isL2 ? W2 : U1;
        #pragma unroll
        for (int g = 0; g < 3; ++g) {
            const int col = g * 64 + ut * 16 + lc;
            #pragma unroll
            for (int kk = 0; kk < 2; ++kk) {
                bf16x8 v;
                #pragma unroll
                for (int e = 0; e < 8; ++e)
                    v[e] = (short)f2bf(M0[(8 * lg + 32 * kk + e) * U3 + col]);
                fb[g * 2 + kk] = v;
            }
        }
        if (isL2) {
            #pragma unroll
            for (int g = 0; g < 3; ++g) {
                const int col = g * 64 + ut * 16 + lc;
                #pragma unroll
                for (int kk = 0; kk < 2; ++kk) {
                    bf16x8 v;
                    #pragma unroll
                    for (int e = 0; e < 8; ++e)
                        v[e] = (short)f2bf(U2[(8 * lg + 32 * kk + e) * U3 + col]);
                    fb[6 + g * 2 + kk] = v;
                }
            }
        } else {
            #pragma unroll
            for (int q = 6; q < 12; ++q) fb[q] = fb[q - 6];  // keep defined
        }
    }

    // biases (per-column, constant over rows)
    float bias_z, bias_r, bias_h, bias_h2 = 0.0f;
    if (!isL2) {
        bias_z = b1[U3 + cz]; bias_r = b1[U3 + cr]; bias_h = b1[U3 + ch];
    } else {
        bias_z  = b2[cz] + b2[U3 + cz];
        bias_r  = b2[cr] + b2[U3 + cr];
        bias_h  = b2[ch];         // xh accumulator init (input-side bias)
        bias_h2 = b2[U3 + ch];    // hph accumulator init (recurrent bias)
    }

    // ---- xp/token prefetch pipeline (L1 waves). Each lane serves its ONE
    // batch row (rb = lg): 3 embW floats + 1 token per step. Static 2-deep
    // rotation via compile-time half index (stays in registers).
    float xp[2][3];
    int   tok[2];
    const int rowbase = (blk * BPB + lg) * TT;   // this lane's token row
    if (!isL2) {
        const int t0 = tokens[rowbase];
        tok[0] = tokens[rowbase + 1];
        tok[1] = tokens[rowbase + 2];
        xp[0][0] = g_embW[t0 * U3 + cz];
        xp[0][1] = g_embW[t0 * U3 + cr];
        xp[0][2] = g_embW[t0 * U3 + ch];
    }

    float h1o = 0.0f;   // h1(s-1) master copy (L1 waves)
    float h2o = 0.0f;   // h2(s-2) master copy (L2 waves)

    __syncthreads();

    const int swzA = (lc & 7) << 4;              // A-read row swizzle (row = lc)
    const int myrow = 4 * lg;                    // this lane's MFMA/LDS row
    const int wswz  = ((myrow & 7) << 4);        // write swizzle for that row
    const int wbyte = myrow * 128 + (((ut * 16 + lc) * 2) ^ wswz);

    #pragma unroll 1
    for (int sb = 0; sb < TT + 1; sb += 2) {      // TT+1 = 4996 steps total
        #pragma unroll
        for (int half = 0; half < 2; ++half) {
            const int s = sb + half;              // step
            char* rdb = hls + half * 4096;        // read buffer
            char* wrb = hls + (half ^ 1) * 4096;  // write buffer

            // A-fragments: rows=batch (lc), k=units. One ds_read_b128 each.
            bf16x8 a1_0 = *(const bf16x8*)(rdb + lc * 128 + ((16 * lg) ^ swzA));
            bf16x8 a1_1 = *(const bf16x8*)(rdb + lc * 128 + ((16 * lg + 64) ^ swzA));
            bf16x8 a2_0 = *(const bf16x8*)(rdb + 2048 + lc * 128 + ((16 * lg) ^ swzA));
            bf16x8 a2_1 = *(const bf16x8*)(rdb + 2048 + lc * 128 + ((16 * lg + 64) ^ swzA));

            if (!isL2) {
                // prefetch xp for step s+1 (uses tok[half] = tokens[s+1]) and
                // the token for s+2 into tok[half^1]
                const int tn = tok[half];
                xp[half ^ 1][0] = g_embW[tn * U3 + cz];
                xp[half ^ 1][1] = g_embW[tn * U3 + cr];
                xp[half ^ 1][2] = g_embW[tn * U3 + ch];
                const int s2 = (s + 2 < TT) ? (s + 2) : (TT - 1);
                tok[half ^ 1] = tokens[rowbase + s2];

                if (s < TT) {   // layer 1 computes h1(s)
                    f32x4 az = {bias_z, bias_z, bias_z, bias_z};
                    f32x4 ar = {bias_r, bias_r, bias_r, bias_r};
                    f32x4 ah = {bias_h, bias_h, bias_h, bias_h};
                    az = MFMA16(a1_0, fb[0], az, 0, 0, 0);
                    az = MFMA16(a1_1, fb[1], az, 0, 0, 0);
                    ar = MFMA16(a1_0, fb[2], ar, 0, 0, 0);
                    ar = MFMA16(a1_1, fb[3], ar, 0, 0, 0);
                    ah = MFMA16(a1_0, fb[4], ah, 0, 0, 0);
                    ah = MFMA16(a1_1, fb[5], ah, 0, 0, 0);
                    // gate math: ONLY reg 0 (row 4*lg = this lane's batch row)
                    const float z  = fast_sigmoid(xp[half][0] + az[0]);
                    const float rg = fast_sigmoid(xp[half][1] + ar[0]);
                    const float hh = fast_tanh(xp[half][2] + rg * ah[0]);
                    h1o = z * h1o + (1.0f - z) * hh;
                    *(unsigned short*)(wrb + wbyte) = f2bf(h1o);
                }
            } else {
                if (s > 0) {    // layer 2 computes h2(s-1)
                    f32x4 az = {bias_z,  bias_z,  bias_z,  bias_z };
                    f32x4 ar = {bias_r,  bias_r,  bias_r,  bias_r };
                    f32x4 ax = {bias_h,  bias_h,  bias_h,  bias_h };
                    f32x4 ap = {bias_h2, bias_h2, bias_h2, bias_h2};
                    az = MFMA16(a1_0, fb[0],  az, 0, 0, 0);   // h1@W2 (z)
                    az = MFMA16(a1_1, fb[1],  az, 0, 0, 0);
                    az = MFMA16(a2_0, fb[6],  az, 0, 0, 0);   // + h2@U2 (z)
                    az = MFMA16(a2_1, fb[7],  az, 0, 0, 0);
                    ar = MFMA16(a1_0, fb[2],  ar, 0, 0, 0);
                    ar = MFMA16(a1_1, fb[3],  ar, 0, 0, 0);
                    ar = MFMA16(a2_0, fb[8],  ar, 0, 0, 0);
                    ar = MFMA16(a2_1, fb[9],  ar, 0, 0, 0);
                    ax = MFMA16(a1_0, fb[4],  ax, 0, 0, 0);   // xh (input side)
                    ax = MFMA16(a1_1, fb[5],  ax, 0, 0, 0);
                    ap = MFMA16(a2_0, fb[10], ap, 0, 0, 0);   // hph (recurrent)
                    ap = MFMA16(a2_1, fb[11], ap, 0, 0, 0);
                    // gate math: ONLY reg 0
                    const float z  = fast_sigmoid(az[0]);
                    const float rg = fast_sigmoid(ar[0]);
                    const float hh = fast_tanh(ax[0] + rg * ap[0]);
                    h2o = z * h2o + (1.0f - z) * hh;
                    *(unsigned short*)(wrb + 2048 + wbyte) = f2bf(h2o);
                }
            }
            __syncthreads();
        }
    }

    // ---- output head: h2(TT-1) sits in buf0/which=1 (step TT wrote buf0).
    // Lane j (0..3) of wave 0 handles batch row j at LDS row 4*j.
    if (wave == 0 && lane < BPB) {
        const int row = 4 * lane;
        float acc = bout[0];
        #pragma unroll 8
        for (int u = 0; u < UU; ++u) {
            const unsigned short hv = *(const unsigned short*)(hls + 2048 +
                row * 128 + ((u * 2) ^ ((row & 7) << 4)));
            acc = fmaf(bf2f(hv), Wout[u], acc);
        }
        out[blk * BPB + lane] = fast_sigmoid(acc);
    }
}

extern "C" void kernel_launch(void* const* d_in, const int* in_sizes, int n_in,
                              void* d_out, int out_size, void* d_ws, size_t ws_size,
                              hipStream_t stream) {
    const int*   tokens = (const int*)  d_in[0];
    const float* emb    = (const float*)d_in[1];
    const float* W1     = (const float*)d_in[2];
    const float* U1w    = (const float*)d_in[3];
    const float* b1     = (const float*)d_in[4];
    const float* W2     = (const float*)d_in[5];
    const float* U2w    = (const float*)d_in[6];
    const float* b2     = (const float*)d_in[7];
    const float* Wout   = (const float*)d_in[8];
    const float* bout   = (const float*)d_in[9];
    float* out = (float*)d_out;

    gru_embw_kernel<<<VV, 192, 0, stream>>>(emb, W1, b1);
    gru_scan_kernel<<<NBLK, 512, 0, stream>>>(tokens, U1w, b1, W2, U2w,
                                              b2, Wout, bout, out);
}